// Round 16
// baseline (226.611 us; speedup 1.0000x reference)
//
#include <hip/hip_runtime.h>
#include <cstdint>
#include <cstddef>

// ---- problem constants (B=2, C=512, H=W=32, G=8, Cg=64, h2=w2=8) ----
#define BATCH 2
#define CCH   512
#define HWPIX 1024           // 32*32
#define SCALE 0.125f         // 64^-0.5
// CPB bias lookup table: F(u,v) on 64x64 grid over [-1.45,1.45]^2 (piecewise-linear MLP
// -> bilinear interp error ~1e-6; |u|,|v| <= log1p(3.143)=1.422 from |tanh|<1).
#define TU0  (-1.45f)
#define TDU  (2.9f/63.0f)
#define TINV (63.0f/2.9f)

typedef short bh8 __attribute__((ext_vector_type(8)));   // 8 x bf16 (4 VGPRs)
typedef float f32x4 __attribute__((ext_vector_type(4)));
typedef unsigned short u16;
typedef u16 us8 __attribute__((ext_vector_type(8)));     // 16B of bf16
typedef u16 us4 __attribute__((ext_vector_type(4)));     // 8B of bf16

__device__ __forceinline__ u16 f2bf(float f){
  unsigned u = __float_as_uint(f);
  unsigned r = (u + 0x7FFFu + ((u>>16)&1u))>>16;   // RNE
  return (u16)r;
}
__device__ __forceinline__ float geluf(float v){ return 0.5f*v*(1.0f + erff(v*0.70710678118654752f)); }

// ------------- prep: cvtw (blocks 0..2399) + bnstat1 (2400..2911) + tabbuild (2912..3167) -------------
__global__ __launch_bounds__(256) void prep_kernel(
    const float* __restrict__ qw, const float* __restrict__ kw, const float* __restrict__ vw,
    const float* __restrict__ ow, const float* __restrict__ m1, const float* __restrict__ m2,
    u16* __restrict__ wdst,
    const float* __restrict__ x, const float* __restrict__ g, const float* __restrict__ bta,
    float* __restrict__ AB,
    const float* __restrict__ w0, const float* __restrict__ b0,
    const float* __restrict__ w1, const float* __restrict__ b1,
    const float* __restrict__ w2, const float* __restrict__ b2,
    float* __restrict__ tab){
  __shared__ float ls[4], lss[4];
  __shared__ float red[16][17];
  int blk = blockIdx.x; int t = threadIdx.x;
  if(blk < 2400){
    // ---- cvtw ----
    int idx = (blk*256 + t)*4;
    if(idx >= 2457600) return;
    const float* src; int off;
    if(idx < 32768){ src=qw; off=idx; }
    else if(idx <   65536){ src=kw; off=idx-32768; }
    else if(idx <   98304){ src=vw; off=idx-65536; }
    else if(idx <  360448){ src=ow; off=idx-98304; }
    else if(idx < 1409024){ src=m1; off=idx-360448; }
    else                  { src=m2; off=idx-1409024; }
    float4 v = *(const float4*)&src[off];
    *(us4*)&wdst[idx] = (us4){f2bf(v.x), f2bf(v.y), f2bf(v.z), f2bf(v.w)};
  } else if(blk < 2912){
    // ---- bnstat (first norm) ----
    int c = blk - 2400;
    float s=0.f, ss=0.f;
    for(int b=0;b<BATCH;b++){
      size_t base = (size_t)b*CCH*HWPIX + (size_t)c*HWPIX;
      for(int p=t;p<HWPIX;p+=256){
        float v = x[base+p];
        s += v; ss += v*v;
      }
    }
    for(int o=32;o;o>>=1){ s += __shfl_down(s,o); ss += __shfl_down(ss,o); }
    int w = t>>6, lane = t&63;
    if(lane==0){ ls[w]=s; lss[w]=ss; }
    __syncthreads();
    if(t==0){
      float S=ls[0]+ls[1]+ls[2]+ls[3], SS=lss[0]+lss[1]+lss[2]+lss[3];
      float m = S*(1.0f/2048.0f);
      float var = SS*(1.0f/2048.0f) - m*m;
      float r = rsqrtf(var + 1e-5f);
      AB[c]     = r*g[c];
      AB[512+c] = bta[c] - m*r*g[c];
    }
  } else {
    // ---- tabbuild ----
    int eloc = t & 15, chunk = t >> 4;
    int e = (blk-2912)*16 + eloc;                // 0..4095
    int iu = e & 63, iv = e >> 6;
    float u = TU0 + iu*TDU, v = TU0 + iv*TDU;
    float acc[8] = {0.f,0.f,0.f,0.f,0.f,0.f,0.f,0.f};
    for(int k=0;k<128;k++){
      float h0 = fmaxf(fmaf(u, w0[k], fmaf(v, w0[128+k], b0[k])), 0.f);
      const float* wr = &w1[k*128 + chunk*8];
      #pragma unroll
      for(int n=0;n<8;n++) acc[n] = fmaf(h0, wr[n], acc[n]);
    }
    float partial = 0.f;
    #pragma unroll
    for(int n=0;n<8;n++)
      partial = fmaf(fmaxf(acc[n] + b1[chunk*8+n], 0.f), w2[chunk*8+n], partial);
    red[eloc][chunk] = partial;
    __syncthreads();
    if(chunk==0){
      float s = b2[0];
      #pragma unroll
      for(int c2=0;c2<16;c2++) s += red[eloc][c2];
      tab[e] = s;
    }
  }
}

// ---------------- BatchNorm stats: per-channel scale/shift -> AB[1024] ----------------
__global__ __launch_bounds__(256) void bnstat_kernel(const float* __restrict__ src,
      const float* __restrict__ g, const float* __restrict__ bta, float* __restrict__ AB){
  int c = blockIdx.x; int t = threadIdx.x;
  float s=0.f, ss=0.f;
  for(int b=0;b<BATCH;b++){
    size_t base = (size_t)b*CCH*HWPIX + (size_t)c*HWPIX;
    for(int p=t;p<HWPIX;p+=256){
      float v = src[base+p];
      s += v; ss += v*v;
    }
  }
  for(int o=32;o;o>>=1){ s += __shfl_down(s,o); ss += __shfl_down(ss,o); }
  __shared__ float ls[4], lss[4];
  int w = t>>6, lane = t&63;
  if(lane==0){ ls[w]=s; lss[w]=ss; }
  __syncthreads();
  if(t==0){
    float S=ls[0]+ls[1]+ls[2]+ls[3], SS=lss[0]+lss[1]+lss[2]+lss[3];
    float m = S*(1.0f/2048.0f);
    float var = SS*(1.0f/2048.0f) - m*m;
    float r = rsqrtf(var + 1e-5f);
    AB[c]     = r*g[c];
    AB[512+c] = bta[c] - m*r*g[c];
  }
}

// ---------------- BN apply + transpose: src [b][ch][p] f32 -> dstT [n][k] bf16 (+opt f32 copy) ----------------
// tMode 0: dstT[(b*8+g)*65536 + p*64 + c]  (grouped, K=64)   tMode 1: dstT[b*524288 + p*512 + g*64 + c]
__global__ __launch_bounds__(256) void bntrans_kernel(const float* __restrict__ src,
      const float* __restrict__ AB, float* __restrict__ dstF, u16* __restrict__ dstT, int tMode){
  __shared__ float tile[64*65];
  int t = threadIdx.x;
  int p0 = blockIdx.x*64, gq = blockIdx.y, b = blockIdx.z;
  int pl = t&63, seg = t>>6;
  #pragma unroll
  for(int r=0;r<16;r++){
    int c = seg*16 + r;
    int ch = gq*64 + c;
    size_t a = (size_t)b*524288 + (size_t)ch*1024 + p0 + pl;
    float v = src[a]*AB[ch] + AB[512+ch];
    tile[c*65 + pl] = v;
    if(dstF) dstF[a] = v;
  }
  __syncthreads();
  int c = t&63;
  #pragma unroll
  for(int r=0;r<16;r++){
    int p = seg*16 + r;
    float v = tile[c*65 + p];
    size_t a = tMode ? ((size_t)b*524288 + (size_t)(p0+p)*512 + gq*64 + c)
                     : ((size_t)(b*8+gq)*65536 + (size_t)(p0+p)*64 + c);
    dstT[a] = f2bf(v);
  }
}

// ------- LDS-staged pipelined GEMM: out[b][m][n] = W[m][k] @ Xt, Xt is [n][k] bf16 -------
// NT = 16-col n-subtiles per wave. TOUT: 0 = f32 [m][n]; 1 = bf16 transposed [n][m];
// 2 = BOTH (f32 [m][n] unscaled + bf16 [n][m] scaled by SCALE — for attention Q).
template<int NT, int TOUT>
__global__ __launch_bounds__(256,4) void gemm_lds(
    const u16* __restrict__ W, const u16* __restrict__ Xt,
    float* __restrict__ outF, u16* __restrict__ outT,
    const float* __restrict__ bias, const float* __restrict__ resF,
    int M, int K, int Nb, int wMask, int wStride, int doGelu){
  __shared__ __align__(16) u16 xS[64*NT*64];   // [row][kb' swizzled], 8*NT KB
  __shared__ __align__(16) u16 wS[64*64];      // 8KB
  int t = threadIdx.x;
  int w = t>>6, lane = t&63, l15 = lane&15, quad = lane>>4;
  int n0 = blockIdx.x*(64*NT), m0 = blockIdx.y*64, batch = blockIdx.z;
  const u16* Wg = W + (size_t)(batch & wMask)*wStride + (size_t)m0*K;
  const u16* Xg = Xt + (size_t)batch*Nb*K + (size_t)n0*K;
  const u16* pX[2*NT]; u16* sX[2*NT];
  #pragma unroll
  for(int p=0;p<2*NT;p++){
    int row = (p*256 + t)>>3, kb = t&7;
    pX[p] = Xg + (size_t)row*K + kb*8;
    sX[p] = &xS[(row*8 + (kb ^ (row&7)))*8];
  }
  int row0 = t>>3,        kb0 = t&7;
  int row1 = (256+t)>>3,  kb1 = t&7;
  const u16* pW0 = Wg + (size_t)row0*K + kb0*8;
  const u16* pW1 = Wg + (size_t)row1*K + kb1*8;
  u16* sW0 = &wS[(row0*8 + (kb0 ^ (row0&7)))*8];
  u16* sW1 = &wS[(row1*8 + (kb1 ^ (row1&7)))*8];
  f32x4 acc[4][NT];
  #pragma unroll
  for(int mt=0;mt<4;mt++)
    #pragma unroll
    for(int nt=0;nt<NT;nt++) acc[mt][nt] = (f32x4){0.f,0.f,0.f,0.f};
  us8 rx[2*NT], rw0, rw1;
  #pragma unroll
  for(int p=0;p<2*NT;p++) rx[p] = *(const us8*)pX[p];
  rw0 = *(const us8*)pW0; rw1 = *(const us8*)pW1;
  for(int kc=0;kc<K;kc+=64){
    #pragma unroll
    for(int p=0;p<2*NT;p++) *(us8*)sX[p] = rx[p];
    *(us8*)sW0 = rw0;  *(us8*)sW1 = rw1;
    __syncthreads();
    if(kc+64 < K){
      #pragma unroll
      for(int p=0;p<2*NT;p++) rx[p] = *(const us8*)(pX[p] + kc+64);
      rw0 = *(const us8*)(pW0 + kc+64);  rw1 = *(const us8*)(pW1 + kc+64);
    }
    #pragma unroll
    for(int ks=0;ks<2;ks++){
      bh8 bF[NT];
      #pragma unroll
      for(int nt=0;nt<NT;nt++){
        int rb = (w*NT + nt)*16 + l15;
        bF[nt] = *(const bh8*)&xS[rb*64 + ((ks*4+quad) ^ (rb&7))*8];
      }
      #pragma unroll
      for(int mt=0;mt<4;mt++){
        int ra = mt*16 + l15;
        bh8 aF = *(const bh8*)&wS[ra*64 + ((ks*4+quad) ^ (ra&7))*8];
        #pragma unroll
        for(int nt=0;nt<NT;nt++)
          acc[mt][nt] = __builtin_amdgcn_mfma_f32_16x16x32_bf16(aF, bF[nt], acc[mt][nt], 0,0,0);
      }
    }
    __syncthreads();
  }
  if(TOUT==1){
    size_t oB = (size_t)batch*Nb*(size_t)M;
    #pragma unroll
    for(int nt=0;nt<NT;nt++){
      int n = n0 + (w*NT + nt)*16 + l15;
      #pragma unroll
      for(int mt=0;mt<4;mt++){
        int m = m0 + mt*16 + quad*4;
        us4 pk;
        #pragma unroll
        for(int reg=0;reg<4;reg++){
          float v = acc[mt][nt][reg];
          if(bias) v += bias[m+reg];
          if(doGelu) v = geluf(v);
          pk[reg] = f2bf(v);
        }
        *(us4*)&outT[oB + (size_t)n*M + m] = pk;
      }
    }
  } else if(TOUT==2){
    size_t oBF = (size_t)batch*(size_t)M*Nb;
    size_t oBT = (size_t)batch*Nb*(size_t)M;
    #pragma unroll
    for(int nt=0;nt<NT;nt++){
      int n = n0 + (w*NT + nt)*16 + l15;
      #pragma unroll
      for(int mt=0;mt<4;mt++){
        int m = m0 + mt*16 + quad*4;
        us4 pk;
        #pragma unroll
        for(int reg=0;reg<4;reg++){
          float v = acc[mt][nt][reg];
          outF[oBF + (size_t)(m+reg)*Nb + n] = v;
          pk[reg] = f2bf(v*SCALE);
        }
        *(us4*)&outT[oBT + (size_t)n*M + m] = pk;
      }
    }
  } else {
    size_t oB = (size_t)batch*(size_t)M*Nb;
    #pragma unroll
    for(int nt=0;nt<NT;nt++){
      int n = n0 + (w*NT + nt)*16 + l15;
      #pragma unroll
      for(int mt=0;mt<4;mt++)
        #pragma unroll
        for(int reg=0;reg<4;reg++){
          int m = m0 + mt*16 + quad*4 + reg;      // C/D: col=lane&15, row=quad*4+reg
          float v = acc[mt][nt][reg];
          if(bias) v += bias[m];
          if(doGelu) v = geluf(v);
          size_t a = oB + (size_t)m*Nb + n;
          if(resF) v += resF[a];
          outF[a] = v;
        }
    }
  }
}

// ------------- depthwise 6x6 stride-4 pad-1 conv + exact gelu -------------
__global__ __launch_bounds__(256) void dwconv_kernel(const float* __restrict__ q,
    const float* __restrict__ dw, const float* __restrict__ dwb, float* __restrict__ offg){
  int t = threadIdx.x;
  int bgc = blockIdx.x*4 + (t>>6);       // 0..1023 = bg*64 + c
  int c = bgc & 63;
  int pix = t&63;
  int oy = pix>>3, ox = pix&7;
  const float* img = q + (size_t)bgc*HWPIX;
  float acc = dwb[c];
  #pragma unroll
  for(int ky=0;ky<6;ky++){
    int y = oy*4 - 1 + ky;
    if(y<0 || y>31) continue;
    #pragma unroll
    for(int kx=0;kx<6;kx++){
      int x = ox*4 - 1 + kx;
      if(x<0 || x>31) continue;
      acc = fmaf(img[y*32 + x], dw[c*36 + ky*6 + kx], acc);
    }
  }
  offg[(size_t)bgc*64 + pix] = geluf(acc);
}

// ------------- fused: pwgrid + bilinear sample + k/v MFMA gemms, one block per bg -------------
// Phase A: vgrid from offg (LDS reduce; also stored to global for biaseval).
// Phase B: sample xn at vgrid -> LDS kv tile [p][c] bf16, gemm-swizzled.
// Phase C: k = kw@kv -> kTb bf16 [j][d]; v = vw@kv -> vbuf f32 [d][j]. W frags direct from global.
__device__ __forceinline__ float fetchpix(const float* img, int ix, int iy){
  return (ix>=0 && ix<32 && iy>=0 && iy<32) ? img[iy*32+ix] : 0.0f;
}
__global__ __launch_bounds__(256) void samplekv_kernel(
    const float* __restrict__ xn, const float* __restrict__ offg, const float* __restrict__ pw,
    const u16* __restrict__ kwb, const u16* __restrict__ vwb,
    float* __restrict__ vgrid, u16* __restrict__ kTb, float* __restrict__ vbuf){
  __shared__ __align__(16) u16 kvS[64*64];   // [p][c swizzled]
  __shared__ float redA[64][5], redB[64][5];
  __shared__ float sVG[128];
  int bg = blockIdx.x; int t = threadIdx.x;
  int p = t&63, cq = t>>6;
  // ---- Phase A: pointwise 64->2 + tanh + grid ----
  float a0=0.f, a1=0.f;
  for(int c=cq*16;c<cq*16+16;c++){
    float v = offg[(size_t)bg*4096 + c*64 + p];
    a0 = fmaf(v, pw[c], a0);
    a1 = fmaf(v, pw[64+c], a1);
  }
  redA[p][cq] = a0; redB[p][cq] = a1;
  __syncthreads();
  if(t < 64){
    float s0 = redA[t][0]+redA[t][1]+redA[t][2]+redA[t][3];
    float s1 = redB[t][0]+redB[t][1]+redB[t][2]+redB[t][3];
    float o0 = tanhf(s0)*4.0f, o1 = tanhf(s1)*4.0f;
    float gx = (float)(t&7), gy = (float)(t>>3);
    float vxx = (2.0f/7.0f)*(gx + o0) - 1.0f;
    float vyy = (2.0f/7.0f)*(gy + o1) - 1.0f;
    sVG[t*2]   = vxx;  sVG[t*2+1] = vyy;
    vgrid[bg*128 + t*2]   = vxx;        // for biaseval
    vgrid[bg*128 + t*2+1] = vyy;
  }
  __syncthreads();
  // ---- Phase B: bilinear sample -> kvS (16 channels per thread, swizzled us8 stores) ----
  {
    float vx = sVG[p*2], vy = sVG[p*2+1];
    float xs = ((vx + 1.0f)*32.0f - 1.0f)*0.5f;
    float ys = ((vy + 1.0f)*32.0f - 1.0f)*0.5f;
    float x0 = floorf(xs), y0 = floorf(ys);
    float wx = xs - x0, wy = ys - y0;
    int ix0 = (int)x0, iy0 = (int)y0;
    int b = bg>>3, g = bg&7;
    float w00 = (1.f-wx)*(1.f-wy), w10 = wx*(1.f-wy), w01 = (1.f-wx)*wy, w11 = wx*wy;
    u16 tmp[16];
    #pragma unroll
    for(int cc=0;cc<16;cc++){
      int c = cq*16 + cc;
      const float* img = xn + (size_t)b*CCH*HWPIX + (size_t)(g*64+c)*HWPIX;
      float acc = w00*fetchpix(img,ix0,iy0)   + w10*fetchpix(img,ix0+1,iy0)
                + w01*fetchpix(img,ix0,iy0+1) + w11*fetchpix(img,ix0+1,iy0+1);
      tmp[cc] = f2bf(acc);
    }
    int kb0 = cq*2, kb1 = cq*2+1;       // c-blocks of 8
    *(us8*)&kvS[p*64 + ((kb0 ^ (p&7))<<3)] = *(us8*)&tmp[0];
    *(us8*)&kvS[p*64 + ((kb1 ^ (p&7))<<3)] = *(us8*)&tmp[8];
  }
  __syncthreads();
  // ---- Phase C: two 64x64x64 MFMA gemms from kvS; W fragments direct from global ----
  int w = t>>6, lane = t&63, l15 = lane&15, quad = lane>>4;
  int g8 = bg&7;
  const u16* kW = kwb + (size_t)g8*4096 + quad*8;
  const u16* vW = vwb + (size_t)g8*4096 + quad*8;
  int rb = w*16 + l15;
  bh8 bF[2];
  #pragma unroll
  for(int ks=0;ks<2;ks++)
    bF[ks] = *(const bh8*)&kvS[rb*64 + ((ks*4+quad) ^ (rb&7))*8];
  // k: out[n=j][m=d] bf16
  {
    f32x4 acc[4];
    #pragma unroll
    for(int mt=0;mt<4;mt++) acc[mt] = (f32x4){0.f,0.f,0.f,0.f};
    #pragma unroll
    for(int ks=0;ks<2;ks++)
      #pragma unroll
      for(int mt=0;mt<4;mt++){
        bh8 aF = *(const bh8*)&kW[(size_t)(mt*16+l15)*64 + ks*32];
        acc[mt] = __builtin_amdgcn_mfma_f32_16x16x32_bf16(aF, bF[ks], acc[mt], 0,0,0);
      }
    int n = w*16 + l15;
    #pragma unroll
    for(int mt=0;mt<4;mt++){
      us4 pk;
      #pragma unroll
      for(int reg=0;reg<4;reg++) pk[reg] = f2bf(acc[mt][reg]);
      *(us4*)&kTb[(size_t)bg*4096 + (size_t)n*64 + mt*16 + quad*4] = pk;
    }
  }
  // v: out[m=d][n=j] f32
  {
    f32x4 acc[4];
    #pragma unroll
    for(int mt=0;mt<4;mt++) acc[mt] = (f32x4){0.f,0.f,0.f,0.f};
    #pragma unroll
    for(int ks=0;ks<2;ks++)
      #pragma unroll
      for(int mt=0;mt<4;mt++){
        bh8 aF = *(const bh8*)&vW[(size_t)(mt*16+l15)*64 + ks*32];
        acc[mt] = __builtin_amdgcn_mfma_f32_16x16x32_bf16(aF, bF[ks], acc[mt], 0,0,0);
      }
    int n = w*16 + l15;
    #pragma unroll
    for(int mt=0;mt<4;mt++)
      #pragma unroll
      for(int reg=0;reg<4;reg++)
        vbuf[(size_t)bg*4096 + (size_t)(mt*16 + quad*4 + reg)*64 + n] = acc[mt][reg];
  }
}

// ------------- CPB bias eval: bilinear interp of tab at (u(px), v(py)) -------------
__global__ __launch_bounds__(256) void biaseval_kernel(
    const float* __restrict__ vgrid, const float* __restrict__ tab,
    float* __restrict__ biasOut){
  int t = threadIdx.x;
  int bg = blockIdx.x >> 6, jj = blockIdx.x & 63;
  float vx = vgrid[bg*128 + jj*2];
  float vy = vgrid[bg*128 + jj*2 + 1];
  int i0 = t*4;
  int gy = i0 >> 5, gx0 = i0 & 31;
  float py = (2.0f/31.0f)*(float)gy - 1.0f - vy;
  float v = copysignf(__logf(1.0f + fabsf(py)), py);
  float fv = (v - TU0) * TINV;
  int iv = (int)floorf(fv);
  iv = iv < 0 ? 0 : (iv > 62 ? 62 : iv);
  fv -= (float)iv;
  f32x4 res;
  #pragma unroll
  for(int c=0;c<4;c++){
    float px = (2.0f/31.0f)*(float)(gx0 + c) - 1.0f - vx;
    float u = copysignf(__logf(1.0f + fabsf(px)), px);
    float fu = (u - TU0) * TINV;
    int iu = (int)floorf(fu);
    iu = iu < 0 ? 0 : (iu > 62 ? 62 : iu);
    fu -= (float)iu;
    const float* p0 = &tab[iv*64 + iu];
    const float* p1 = p0 + 64;
    float a = fmaf(fu, p0[1] - p0[0], p0[0]);
    float b = fmaf(fu, p1[1] - p1[0], p1[0]);
    res[c] = fmaf(fv, b - a, a);
  }
  *(f32x4*)&biasOut[(size_t)bg*65536 + (size_t)jj*1024 + i0] = res;
}

// ------------- MFMA attention: O = softmax(Q·K^T + bias) V -------------
__global__ __launch_bounds__(256) void attn_kernel(
    const u16* __restrict__ qTb, const u16* __restrict__ kTb, const float* __restrict__ vb,
    const float* __restrict__ biasb, u16* __restrict__ obT){
  __shared__ __align__(16) u16 qS[64*64], kS[64*64];   // swizzled (gemm pattern)
  __shared__ __align__(16) u16 vS[64*72], pS[64*72];   // pad-72 rows
  int t = threadIdx.x;
  int w = t>>6, lane = t&63, l15 = lane&15, quad = lane>>4;
  int bg = blockIdx.x>>4, itile = blockIdx.x&15;
  int i0 = itile*64;
  #pragma unroll
  for(int p=0;p<2;p++){
    int idx = p*256 + t;
    int row = idx>>3, kb = t&7;
    int sw = ((kb ^ (row&7)))*8;
    *(us8*)&qS[row*64 + sw] = *(const us8*)&qTb[(size_t)bg*65536 + (size_t)(i0+row)*64 + kb*8];
    *(us8*)&kS[row*64 + sw] = *(const us8*)&kTb[(size_t)bg*4096  + (size_t)row*64      + kb*8];
  }
  for(int e=t;e<4096;e+=256){
    int d = e>>6, j = e&63;
    vS[d*72 + j] = f2bf(vb[(size_t)bg*4096 + e]);
  }
  __syncthreads();
  f32x4 sAcc[4];
  #pragma unroll
  for(int jt=0;jt<4;jt++){
    int jg = jt*16 + l15;
    sAcc[jt] = *(const f32x4*)&biasb[(size_t)bg*65536 + (size_t)jg*1024 + i0 + w*16 + quad*4];
  }
  int ra = w*16 + l15;
  #pragma unroll
  for(int ks=0;ks<2;ks++){
    bh8 aF = *(const bh8*)&qS[ra*64 + ((ks*4+quad) ^ (ra&7))*8];
    #pragma unroll
    for(int jt=0;jt<4;jt++){
      int rb = jt*16 + l15;
      bh8 bF = *(const bh8*)&kS[rb*64 + ((ks*4+quad) ^ (rb&7))*8];
      sAcc[jt] = __builtin_amdgcn_mfma_f32_16x16x32_bf16(aF, bF, sAcc[jt], 0,0,0);
    }
  }
  #pragma unroll
  for(int reg=0;reg<4;reg++){
    float m = fmaxf(fmaxf(sAcc[0][reg], sAcc[1][reg]), fmaxf(sAcc[2][reg], sAcc[3][reg]));
    m = fmaxf(m, __shfl_xor(m, 1));
    m = fmaxf(m, __shfl_xor(m, 2));
    m = fmaxf(m, __shfl_xor(m, 4));
    m = fmaxf(m, __shfl_xor(m, 8));
    float li = 0.f;
    #pragma unroll
    for(int jt=0;jt<4;jt++){
      float e = __expf(sAcc[jt][reg] - m);
      sAcc[jt][reg] = e;
      li += e;
    }
    li += __shfl_xor(li, 1);
    li += __shfl_xor(li, 2);
    li += __shfl_xor(li, 4);
    li += __shfl_xor(li, 8);
    float inv = 1.0f / li;
    #pragma unroll
    for(int jt=0;jt<4;jt++) sAcc[jt][reg] *= inv;
  }
  #pragma unroll
  for(int jt=0;jt<4;jt++)
    #pragma unroll
    for(int reg=0;reg<4;reg++)
      pS[(w*16 + quad*4 + reg)*72 + jt*16 + l15] = f2bf(sAcc[jt][reg]);
  __syncthreads();
  f32x4 oAcc[4];
  #pragma unroll
  for(int dt=0;dt<4;dt++) oAcc[dt] = (f32x4){0.f,0.f,0.f,0.f};
  int rp = w*16 + l15;
  #pragma unroll
  for(int ks=0;ks<2;ks++){
    bh8 aP = *(const bh8*)&pS[rp*72 + ks*32 + quad*8];
    #pragma unroll
    for(int dt=0;dt<4;dt++){
      bh8 bV = *(const bh8*)&vS[(dt*16 + l15)*72 + ks*32 + quad*8];
      oAcc[dt] = __builtin_amdgcn_mfma_f32_16x16x32_bf16(aP, bV, oAcc[dt], 0,0,0);
    }
  }
  int b = bg>>3, g = bg&7;
  #pragma unroll
  for(int dt=0;dt<4;dt++)
    #pragma unroll
    for(int reg=0;reg<4;reg++){
      int i = i0 + w*16 + quad*4 + reg;
      obT[(size_t)b*524288 + (size_t)i*512 + g*64 + dt*16 + l15] = f2bf(oAcc[dt][reg]);
    }
}

extern "C" void kernel_launch(void* const* d_in, const int* in_sizes, int n_in,
                              void* d_out, int out_size, void* d_ws, size_t ws_size,
                              hipStream_t stream){
  const float* x    = (const float*)d_in[0];
  const float* n1g  = (const float*)d_in[1];
  const float* n1b  = (const float*)d_in[2];
  const float* n2g  = (const float*)d_in[3];
  const float* n2b  = (const float*)d_in[4];
  const float* qw   = (const float*)d_in[5];
  const float* kw   = (const float*)d_in[6];
  const float* vw   = (const float*)d_in[7];
  const float* dww  = (const float*)d_in[8];
  const float* dwb  = (const float*)d_in[9];
  const float* pww  = (const float*)d_in[10];
  const float* cw0  = (const float*)d_in[11];
  const float* cb0  = (const float*)d_in[12];
  const float* cw1  = (const float*)d_in[13];
  const float* cb1  = (const float*)d_in[14];
  const float* cw2  = (const float*)d_in[15];
  const float* cb2  = (const float*)d_in[16];
  const float* ow   = (const float*)d_in[17];
  const float* obb  = (const float*)d_in[18];
  const float* m1w  = (const float*)d_in[19];
  const float* m1bi = (const float*)d_in[20];
  const float* m2w  = (const float*)d_in[21];
  const float* m2bi = (const float*)d_in[22];
  float* out = (float*)d_out;          // reference output dtype is float32
  float* ws = (float*)d_ws;

  float* xn     = ws;                       // 1M f32: bn1 normalized (c-major, for sample)
  float* x2     = ws + 1048576;             // 1M f32: outproj out (res for mlp2, src for bn2)
  float* q      = ws + 2097152;             // 1M f32 [bg][c][p], dead after dwconv
  float* biasb  = ws + 3145728;             // 1M f32, dead after attn
  u16*   hT     = (u16*)(ws + 2097152);     // 4M u16 over dead {q,biasb}: mlp1 out [b][p][c2048]
  u16*   attnT  = (u16*)(ws + 4194304);     // 1M u16: attn out [b][p][c512]
  u16*   xnT    = (u16*)(ws + 4718592);     // 1M u16: bn1 T [bg][p][c64]; reused as bn2 T [b][p][c512]
  float* tab    = ws + 5242880;             // 4096 f32 CPB table
  u16*   kTb    = (u16*)(ws + 5275648);     // 64K u16: k bf16 [bg][j][d]
  float* vbuf   = ws + 5341184;             // 64K f32 [bg][d][j]
  float* offg   = ws + 5406720;             // 64K f32 (aliased as bn stats when offg dead)
  float* bnAB   = offg;                     // 1024 f32 alias (disjoint lifetime)
  float* vgrid  = ws + 5472256;             // 2K f32
  u16*   wbf    = (u16*)(ws + 5474304);     // 2457600 u16 bf16 weights
  u16*   qTb    = (u16*)(ws + 6703104);     // 1M u16: q bf16 [bg][p][d], pre-scaled by 0.125
  u16 *qwb = wbf, *kwb = wbf+32768, *vwb = wbf+65536, *owb = wbf+98304;
  u16 *m1wb = wbf+360448, *m2wb = wbf+1409024;

  // prep: cvtw (2400) + bnstat1 (512) + tabbuild (256) in one dispatch
  prep_kernel<<<3168,256,0,stream>>>(qw,kw,vw,ow,m1w,m2w,wbf,
                                     x,n1g,n1b,bnAB,
                                     cw0,cb0,cw1,cb1,cw2,cb2,tab);
  bntrans_kernel<<<dim3(16,8,2),256,0,stream>>>(x, bnAB, xn, xnT, 0);
  // q: dual output — f32 [bg][c][p] for dwconv + bf16 [bg][p][d] (x0.125) for MFMA attn
  gemm_lds<1,2><<<dim3(16,1,16),256,0,stream>>>(qwb, xnT, q, qTb, nullptr, nullptr,
                                                64,64,1024, 7, 4096, 0);
  dwconv_kernel<<<256,256,0,stream>>>(q, dww, dwb, offg);
  // fused pwgrid + sample + k-gemm + v-gemm (per-bg blocks; kv tile lives in LDS)
  samplekv_kernel<<<16,256,0,stream>>>(xn, offg, pww, kwb, vwb, vgrid, kTb, vbuf);
  biaseval_kernel<<<1024,256,0,stream>>>(vgrid, tab, biasb);
  attn_kernel<<<256,256,0,stream>>>(qTb, kTb, vbuf, biasb, attnT);
  gemm_lds<1,0><<<dim3(16,8,2),256,0,stream>>>(owb, attnT, x2, nullptr, obb, x,
                                               512,512,1024, 0,0,0);
  bnstat_kernel<<<512,256,0,stream>>>(x2, n2g, n2b, bnAB);
  bntrans_kernel<<<dim3(16,8,2),256,0,stream>>>(x2, bnAB, nullptr, xnT, 1);
  // mlp1: NT=2 (64m x 128n tile), grid 512 blocks
  gemm_lds<2,1><<<dim3(8,32,2),256,0,stream>>>(m1wb, xnT, nullptr, hT, m1bi, nullptr,
                                               2048,512,1024, 0,0,1);
  gemm_lds<1,0><<<dim3(16,8,2),256,0,stream>>>(m2wb, hT, out, nullptr, m2bi, x2,
                                               512,2048,1024, 0,0,0);
}

// Round 17
// 211.282 us; speedup vs baseline: 1.0726x; 1.0726x over previous
//
#include <hip/hip_runtime.h>
#include <cstdint>
#include <cstddef>

// ---- problem constants (B=2, C=512, H=W=32, G=8, Cg=64, h2=w2=8) ----
#define BATCH 2
#define CCH   512
#define HWPIX 1024           // 32*32
#define SCALE 0.125f         // 64^-0.5
// CPB bias lookup table: F(u,v) on 64x64 grid over [-1.45,1.45]^2 (piecewise-linear MLP
// -> bilinear interp error ~1e-6; |u|,|v| <= log1p(3.143)=1.422 from |tanh|<1).
#define TU0  (-1.45f)
#define TDU  (2.9f/63.0f)
#define TINV (63.0f/2.9f)

typedef short bh8 __attribute__((ext_vector_type(8)));   // 8 x bf16 (4 VGPRs)
typedef float f32x4 __attribute__((ext_vector_type(4)));
typedef unsigned short u16;
typedef u16 us8 __attribute__((ext_vector_type(8)));     // 16B of bf16
typedef u16 us4 __attribute__((ext_vector_type(4)));     // 8B of bf16

__device__ __forceinline__ u16 f2bf(float f){
  unsigned u = __float_as_uint(f);
  unsigned r = (u + 0x7FFFu + ((u>>16)&1u))>>16;   // RNE
  return (u16)r;
}
__device__ __forceinline__ float geluf(float v){ return 0.5f*v*(1.0f + erff(v*0.70710678118654752f)); }

// ------------- prep: cvtw (blocks 0..2399) + bnstat1 (2400..2911) + tabbuild (2912..3167) -------------
// tabbuild v2: w1 staged to LDS in 16KB chunks (coalesced, read-once) + h0 precomputed in LDS
// -> accumulate loop touches LDS only. (v1's 128-iter global-load chain was 47 us latency-bound.)
__global__ __launch_bounds__(256) void prep_kernel(
    const float* __restrict__ qw, const float* __restrict__ kw, const float* __restrict__ vw,
    const float* __restrict__ ow, const float* __restrict__ m1, const float* __restrict__ m2,
    u16* __restrict__ wdst,
    const float* __restrict__ x, const float* __restrict__ g, const float* __restrict__ bta,
    float* __restrict__ AB,
    const float* __restrict__ w0, const float* __restrict__ b0,
    const float* __restrict__ w1, const float* __restrict__ b1,
    const float* __restrict__ w2, const float* __restrict__ b2,
    float* __restrict__ tab){
  __shared__ float ls[4], lss[4];
  __shared__ float red[16][17];
  __shared__ __align__(16) float w1s[4096];   // 16 KB w1 chunk
  __shared__ float h0s[16*33];                // h0: 16 entries x 32 k (pad 33)
  int blk = blockIdx.x; int t = threadIdx.x;
  if(blk < 2400){
    // ---- cvtw ----
    int idx = (blk*256 + t)*4;
    if(idx >= 2457600) return;
    const float* src; int off;
    if(idx < 32768){ src=qw; off=idx; }
    else if(idx <   65536){ src=kw; off=idx-32768; }
    else if(idx <   98304){ src=vw; off=idx-65536; }
    else if(idx <  360448){ src=ow; off=idx-98304; }
    else if(idx < 1409024){ src=m1; off=idx-360448; }
    else                  { src=m2; off=idx-1409024; }
    float4 v = *(const float4*)&src[off];
    *(us4*)&wdst[idx] = (us4){f2bf(v.x), f2bf(v.y), f2bf(v.z), f2bf(v.w)};
  } else if(blk < 2912){
    // ---- bnstat (first norm) ----
    int c = blk - 2400;
    float s=0.f, ss=0.f;
    for(int b=0;b<BATCH;b++){
      size_t base = (size_t)b*CCH*HWPIX + (size_t)c*HWPIX;
      for(int p=t;p<HWPIX;p+=256){
        float v = x[base+p];
        s += v; ss += v*v;
      }
    }
    for(int o=32;o;o>>=1){ s += __shfl_down(s,o); ss += __shfl_down(ss,o); }
    int w = t>>6, lane = t&63;
    if(lane==0){ ls[w]=s; lss[w]=ss; }
    __syncthreads();
    if(t==0){
      float S=ls[0]+ls[1]+ls[2]+ls[3], SS=lss[0]+lss[1]+lss[2]+lss[3];
      float m = S*(1.0f/2048.0f);
      float var = SS*(1.0f/2048.0f) - m*m;
      float r = rsqrtf(var + 1e-5f);
      AB[c]     = r*g[c];
      AB[512+c] = bta[c] - m*r*g[c];
    }
  } else {
    // ---- tabbuild v2 (LDS-staged) ----
    int eloc = t & 15, chunk = t >> 4;           // 16 entries x 16 n-chunks of 8
    int eb = (blk-2912)*16;
    int e = eb + eloc;
    float acc[8] = {0.f,0.f,0.f,0.f,0.f,0.f,0.f,0.f};
    for(int kc=0;kc<128;kc+=32){
      #pragma unroll
      for(int r=0;r<4;r++){
        int idx = r*1024 + t*4;
        *(f32x4*)&w1s[idx] = *(const f32x4*)&w1[kc*128 + idx];
      }
      #pragma unroll
      for(int j=0;j<2;j++){
        int job = j*256 + t;
        int el = job & 15, kk = job >> 4;        // kk 0..31
        int ee = eb + el;
        float uu = TU0 + (float)(ee&63)*TDU;
        float vv = TU0 + (float)(ee>>6)*TDU;
        int k = kc + kk;
        h0s[el*33 + kk] = fmaxf(fmaf(uu, w0[k], fmaf(vv, w0[128+k], b0[k])), 0.f);
      }
      __syncthreads();
      #pragma unroll 8
      for(int kk=0;kk<32;kk++){
        float h = h0s[eloc*33 + kk];
        const float* wr = &w1s[kk*128 + chunk*8];
        #pragma unroll
        for(int n=0;n<8;n++) acc[n] = fmaf(h, wr[n], acc[n]);
      }
      __syncthreads();
    }
    float partial = 0.f;
    #pragma unroll
    for(int n=0;n<8;n++)
      partial = fmaf(fmaxf(acc[n] + b1[chunk*8+n], 0.f), w2[chunk*8+n], partial);
    red[eloc][chunk] = partial;
    __syncthreads();
    if(chunk==0){
      float s = b2[0];
      #pragma unroll
      for(int c2=0;c2<16;c2++) s += red[eloc][c2];
      tab[e] = s;
    }
  }
}

// ---------------- BatchNorm stats: per-channel scale/shift -> AB[1024] ----------------
__global__ __launch_bounds__(256) void bnstat_kernel(const float* __restrict__ src,
      const float* __restrict__ g, const float* __restrict__ bta, float* __restrict__ AB){
  int c = blockIdx.x; int t = threadIdx.x;
  float s=0.f, ss=0.f;
  for(int b=0;b<BATCH;b++){
    size_t base = (size_t)b*CCH*HWPIX + (size_t)c*HWPIX;
    for(int p=t;p<HWPIX;p+=256){
      float v = src[base+p];
      s += v; ss += v*v;
    }
  }
  for(int o=32;o;o>>=1){ s += __shfl_down(s,o); ss += __shfl_down(ss,o); }
  __shared__ float ls[4], lss[4];
  int w = t>>6, lane = t&63;
  if(lane==0){ ls[w]=s; lss[w]=ss; }
  __syncthreads();
  if(t==0){
    float S=ls[0]+ls[1]+ls[2]+ls[3], SS=lss[0]+lss[1]+lss[2]+lss[3];
    float m = S*(1.0f/2048.0f);
    float var = SS*(1.0f/2048.0f) - m*m;
    float r = rsqrtf(var + 1e-5f);
    AB[c]     = r*g[c];
    AB[512+c] = bta[c] - m*r*g[c];
  }
}

// ---------------- BN apply + transpose: src [b][ch][p] f32 -> dstT [n][k] bf16 (+opt f32 copy) ----------------
// tMode 0: dstT[(b*8+g)*65536 + p*64 + c]  (grouped, K=64)   tMode 1: dstT[b*524288 + p*512 + g*64 + c]
__global__ __launch_bounds__(256) void bntrans_kernel(const float* __restrict__ src,
      const float* __restrict__ AB, float* __restrict__ dstF, u16* __restrict__ dstT, int tMode){
  __shared__ float tile[64*65];
  int t = threadIdx.x;
  int p0 = blockIdx.x*64, gq = blockIdx.y, b = blockIdx.z;
  int pl = t&63, seg = t>>6;
  #pragma unroll
  for(int r=0;r<16;r++){
    int c = seg*16 + r;
    int ch = gq*64 + c;
    size_t a = (size_t)b*524288 + (size_t)ch*1024 + p0 + pl;
    float v = src[a]*AB[ch] + AB[512+ch];
    tile[c*65 + pl] = v;
    if(dstF) dstF[a] = v;
  }
  __syncthreads();
  int c = t&63;
  #pragma unroll
  for(int r=0;r<16;r++){
    int p = seg*16 + r;
    float v = tile[c*65 + p];
    size_t a = tMode ? ((size_t)b*524288 + (size_t)(p0+p)*512 + gq*64 + c)
                     : ((size_t)(b*8+gq)*65536 + (size_t)(p0+p)*64 + c);
    dstT[a] = f2bf(v);
  }
}

// ------- LDS-staged pipelined GEMM: out[b][m][n] = W[m][k] @ Xt, Xt is [n][k] bf16 -------
// NT = 16-col n-subtiles per wave. TOUT: 0 = f32 [m][n]; 1 = bf16 transposed [n][m];
// 2 = BOTH (f32 [m][n] unscaled + bf16 [n][m] scaled by SCALE — for attention Q).
template<int NT, int TOUT>
__global__ __launch_bounds__(256,4) void gemm_lds(
    const u16* __restrict__ W, const u16* __restrict__ Xt,
    float* __restrict__ outF, u16* __restrict__ outT,
    const float* __restrict__ bias, const float* __restrict__ resF,
    int M, int K, int Nb, int wMask, int wStride, int doGelu){
  __shared__ __align__(16) u16 xS[64*NT*64];   // [row][kb' swizzled], 8*NT KB
  __shared__ __align__(16) u16 wS[64*64];      // 8KB
  int t = threadIdx.x;
  int w = t>>6, lane = t&63, l15 = lane&15, quad = lane>>4;
  int n0 = blockIdx.x*(64*NT), m0 = blockIdx.y*64, batch = blockIdx.z;
  const u16* Wg = W + (size_t)(batch & wMask)*wStride + (size_t)m0*K;
  const u16* Xg = Xt + (size_t)batch*Nb*K + (size_t)n0*K;
  const u16* pX[2*NT]; u16* sX[2*NT];
  #pragma unroll
  for(int p=0;p<2*NT;p++){
    int row = (p*256 + t)>>3, kb = t&7;
    pX[p] = Xg + (size_t)row*K + kb*8;
    sX[p] = &xS[(row*8 + (kb ^ (row&7)))*8];
  }
  int row0 = t>>3,        kb0 = t&7;
  int row1 = (256+t)>>3,  kb1 = t&7;
  const u16* pW0 = Wg + (size_t)row0*K + kb0*8;
  const u16* pW1 = Wg + (size_t)row1*K + kb1*8;
  u16* sW0 = &wS[(row0*8 + (kb0 ^ (row0&7)))*8];
  u16* sW1 = &wS[(row1*8 + (kb1 ^ (row1&7)))*8];
  f32x4 acc[4][NT];
  #pragma unroll
  for(int mt=0;mt<4;mt++)
    #pragma unroll
    for(int nt=0;nt<NT;nt++) acc[mt][nt] = (f32x4){0.f,0.f,0.f,0.f};
  us8 rx[2*NT], rw0, rw1;
  #pragma unroll
  for(int p=0;p<2*NT;p++) rx[p] = *(const us8*)pX[p];
  rw0 = *(const us8*)pW0; rw1 = *(const us8*)pW1;
  for(int kc=0;kc<K;kc+=64){
    #pragma unroll
    for(int p=0;p<2*NT;p++) *(us8*)sX[p] = rx[p];
    *(us8*)sW0 = rw0;  *(us8*)sW1 = rw1;
    __syncthreads();
    if(kc+64 < K){
      #pragma unroll
      for(int p=0;p<2*NT;p++) rx[p] = *(const us8*)(pX[p] + kc+64);
      rw0 = *(const us8*)(pW0 + kc+64);  rw1 = *(const us8*)(pW1 + kc+64);
    }
    #pragma unroll
    for(int ks=0;ks<2;ks++){
      bh8 bF[NT];
      #pragma unroll
      for(int nt=0;nt<NT;nt++){
        int rb = (w*NT + nt)*16 + l15;
        bF[nt] = *(const bh8*)&xS[rb*64 + ((ks*4+quad) ^ (rb&7))*8];
      }
      #pragma unroll
      for(int mt=0;mt<4;mt++){
        int ra = mt*16 + l15;
        bh8 aF = *(const bh8*)&wS[ra*64 + ((ks*4+quad) ^ (ra&7))*8];
        #pragma unroll
        for(int nt=0;nt<NT;nt++)
          acc[mt][nt] = __builtin_amdgcn_mfma_f32_16x16x32_bf16(aF, bF[nt], acc[mt][nt], 0,0,0);
      }
    }
    __syncthreads();
  }
  if(TOUT==1){
    size_t oB = (size_t)batch*Nb*(size_t)M;
    #pragma unroll
    for(int nt=0;nt<NT;nt++){
      int n = n0 + (w*NT + nt)*16 + l15;
      #pragma unroll
      for(int mt=0;mt<4;mt++){
        int m = m0 + mt*16 + quad*4;
        us4 pk;
        #pragma unroll
        for(int reg=0;reg<4;reg++){
          float v = acc[mt][nt][reg];
          if(bias) v += bias[m+reg];
          if(doGelu) v = geluf(v);
          pk[reg] = f2bf(v);
        }
        *(us4*)&outT[oB + (size_t)n*M + m] = pk;
      }
    }
  } else if(TOUT==2){
    size_t oBF = (size_t)batch*(size_t)M*Nb;
    size_t oBT = (size_t)batch*Nb*(size_t)M;
    #pragma unroll
    for(int nt=0;nt<NT;nt++){
      int n = n0 + (w*NT + nt)*16 + l15;
      #pragma unroll
      for(int mt=0;mt<4;mt++){
        int m = m0 + mt*16 + quad*4;
        us4 pk;
        #pragma unroll
        for(int reg=0;reg<4;reg++){
          float v = acc[mt][nt][reg];
          outF[oBF + (size_t)(m+reg)*Nb + n] = v;
          pk[reg] = f2bf(v*SCALE);
        }
        *(us4*)&outT[oBT + (size_t)n*M + m] = pk;
      }
    }
  } else {
    size_t oB = (size_t)batch*(size_t)M*Nb;
    #pragma unroll
    for(int nt=0;nt<NT;nt++){
      int n = n0 + (w*NT + nt)*16 + l15;
      #pragma unroll
      for(int mt=0;mt<4;mt++)
        #pragma unroll
        for(int reg=0;reg<4;reg++){
          int m = m0 + mt*16 + quad*4 + reg;      // C/D: col=lane&15, row=quad*4+reg
          float v = acc[mt][nt][reg];
          if(bias) v += bias[m];
          if(doGelu) v = geluf(v);
          size_t a = oB + (size_t)m*Nb + n;
          if(resF) v += resF[a];
          outF[a] = v;
        }
    }
  }
}

// ------------- depthwise 6x6 stride-4 pad-1 conv + exact gelu -------------
__global__ __launch_bounds__(256) void dwconv_kernel(const float* __restrict__ q,
    const float* __restrict__ dw, const float* __restrict__ dwb, float* __restrict__ offg){
  int t = threadIdx.x;
  int bgc = blockIdx.x*4 + (t>>6);       // 0..1023 = bg*64 + c
  int c = bgc & 63;
  int pix = t&63;
  int oy = pix>>3, ox = pix&7;
  const float* img = q + (size_t)bgc*HWPIX;
  float acc = dwb[c];
  #pragma unroll
  for(int ky=0;ky<6;ky++){
    int y = oy*4 - 1 + ky;
    if(y<0 || y>31) continue;
    #pragma unroll
    for(int kx=0;kx<6;kx++){
      int x = ox*4 - 1 + kx;
      if(x<0 || x>31) continue;
      acc = fmaf(img[y*32 + x], dw[c*36 + ky*6 + kx], acc);
    }
  }
  offg[(size_t)bgc*64 + pix] = geluf(acc);
}

// ------------- fused: pwgrid + bilinear sample + k/v MFMA gemms, one block per bg -------------
__device__ __forceinline__ float fetchpix(const float* img, int ix, int iy){
  return (ix>=0 && ix<32 && iy>=0 && iy<32) ? img[iy*32+ix] : 0.0f;
}
__global__ __launch_bounds__(256) void samplekv_kernel(
    const float* __restrict__ xn, const float* __restrict__ offg, const float* __restrict__ pw,
    const u16* __restrict__ kwb, const u16* __restrict__ vwb,
    float* __restrict__ vgrid, u16* __restrict__ kTb, float* __restrict__ vbuf){
  __shared__ __align__(16) u16 kvS[64*64];   // [p][c swizzled]
  __shared__ float redA[64][5], redB[64][5];
  __shared__ float sVG[128];
  int bg = blockIdx.x; int t = threadIdx.x;
  int p = t&63, cq = t>>6;
  // ---- Phase A: pointwise 64->2 + tanh + grid ----
  float a0=0.f, a1=0.f;
  for(int c=cq*16;c<cq*16+16;c++){
    float v = offg[(size_t)bg*4096 + c*64 + p];
    a0 = fmaf(v, pw[c], a0);
    a1 = fmaf(v, pw[64+c], a1);
  }
  redA[p][cq] = a0; redB[p][cq] = a1;
  __syncthreads();
  if(t < 64){
    float s0 = redA[t][0]+redA[t][1]+redA[t][2]+redA[t][3];
    float s1 = redB[t][0]+redB[t][1]+redB[t][2]+redB[t][3];
    float o0 = tanhf(s0)*4.0f, o1 = tanhf(s1)*4.0f;
    float gx = (float)(t&7), gy = (float)(t>>3);
    float vxx = (2.0f/7.0f)*(gx + o0) - 1.0f;
    float vyy = (2.0f/7.0f)*(gy + o1) - 1.0f;
    sVG[t*2]   = vxx;  sVG[t*2+1] = vyy;
    vgrid[bg*128 + t*2]   = vxx;        // for biaseval
    vgrid[bg*128 + t*2+1] = vyy;
  }
  __syncthreads();
  // ---- Phase B: bilinear sample -> kvS (16 channels per thread, swizzled us8 stores) ----
  {
    float vx = sVG[p*2], vy = sVG[p*2+1];
    float xs = ((vx + 1.0f)*32.0f - 1.0f)*0.5f;
    float ys = ((vy + 1.0f)*32.0f - 1.0f)*0.5f;
    float x0 = floorf(xs), y0 = floorf(ys);
    float wx = xs - x0, wy = ys - y0;
    int ix0 = (int)x0, iy0 = (int)y0;
    int b = bg>>3, g = bg&7;
    float w00 = (1.f-wx)*(1.f-wy), w10 = wx*(1.f-wy), w01 = (1.f-wx)*wy, w11 = wx*wy;
    u16 tmp[16];
    #pragma unroll
    for(int cc=0;cc<16;cc++){
      int c = cq*16 + cc;
      const float* img = xn + (size_t)b*CCH*HWPIX + (size_t)(g*64+c)*HWPIX;
      float acc = w00*fetchpix(img,ix0,iy0)   + w10*fetchpix(img,ix0+1,iy0)
                + w01*fetchpix(img,ix0,iy0+1) + w11*fetchpix(img,ix0+1,iy0+1);
      tmp[cc] = f2bf(acc);
    }
    int kb0 = cq*2, kb1 = cq*2+1;       // c-blocks of 8
    *(us8*)&kvS[p*64 + ((kb0 ^ (p&7))<<3)] = *(us8*)&tmp[0];
    *(us8*)&kvS[p*64 + ((kb1 ^ (p&7))<<3)] = *(us8*)&tmp[8];
  }
  __syncthreads();
  // ---- Phase C: two 64x64x64 MFMA gemms from kvS; W fragments direct from global ----
  int w = t>>6, lane = t&63, l15 = lane&15, quad = lane>>4;
  int g8 = bg&7;
  const u16* kW = kwb + (size_t)g8*4096 + quad*8;
  const u16* vW = vwb + (size_t)g8*4096 + quad*8;
  int rb = w*16 + l15;
  bh8 bF[2];
  #pragma unroll
  for(int ks=0;ks<2;ks++)
    bF[ks] = *(const bh8*)&kvS[rb*64 + ((ks*4+quad) ^ (rb&7))*8];
  // k: out[n=j][m=d] bf16
  {
    f32x4 acc[4];
    #pragma unroll
    for(int mt=0;mt<4;mt++) acc[mt] = (f32x4){0.f,0.f,0.f,0.f};
    #pragma unroll
    for(int ks=0;ks<2;ks++)
      #pragma unroll
      for(int mt=0;mt<4;mt++){
        bh8 aF = *(const bh8*)&kW[(size_t)(mt*16+l15)*64 + ks*32];
        acc[mt] = __builtin_amdgcn_mfma_f32_16x16x32_bf16(aF, bF[ks], acc[mt], 0,0,0);
      }
    int n = w*16 + l15;
    #pragma unroll
    for(int mt=0;mt<4;mt++){
      us4 pk;
      #pragma unroll
      for(int reg=0;reg<4;reg++) pk[reg] = f2bf(acc[mt][reg]);
      *(us4*)&kTb[(size_t)bg*4096 + (size_t)n*64 + mt*16 + quad*4] = pk;
    }
  }
  // v: out[m=d][n=j] f32
  {
    f32x4 acc[4];
    #pragma unroll
    for(int mt=0;mt<4;mt++) acc[mt] = (f32x4){0.f,0.f,0.f,0.f};
    #pragma unroll
    for(int ks=0;ks<2;ks++)
      #pragma unroll
      for(int mt=0;mt<4;mt++){
        bh8 aF = *(const bh8*)&vW[(size_t)(mt*16+l15)*64 + ks*32];
        acc[mt] = __builtin_amdgcn_mfma_f32_16x16x32_bf16(aF, bF[ks], acc[mt], 0,0,0);
      }
    int n = w*16 + l15;
    #pragma unroll
    for(int mt=0;mt<4;mt++)
      #pragma unroll
      for(int reg=0;reg<4;reg++)
        vbuf[(size_t)bg*4096 + (size_t)(mt*16 + quad*4 + reg)*64 + n] = acc[mt][reg];
  }
}

// ------------- CPB bias eval: bilinear interp of tab at (u(px), v(py)) -------------
__global__ __launch_bounds__(256) void biaseval_kernel(
    const float* __restrict__ vgrid, const float* __restrict__ tab,
    float* __restrict__ biasOut){
  int t = threadIdx.x;
  int bg = blockIdx.x >> 6, jj = blockIdx.x & 63;
  float vx = vgrid[bg*128 + jj*2];
  float vy = vgrid[bg*128 + jj*2 + 1];
  int i0 = t*4;
  int gy = i0 >> 5, gx0 = i0 & 31;
  float py = (2.0f/31.0f)*(float)gy - 1.0f - vy;
  float v = copysignf(__logf(1.0f + fabsf(py)), py);
  float fv = (v - TU0) * TINV;
  int iv = (int)floorf(fv);
  iv = iv < 0 ? 0 : (iv > 62 ? 62 : iv);
  fv -= (float)iv;
  f32x4 res;
  #pragma unroll
  for(int c=0;c<4;c++){
    float px = (2.0f/31.0f)*(float)(gx0 + c) - 1.0f - vx;
    float u = copysignf(__logf(1.0f + fabsf(px)), px);
    float fu = (u - TU0) * TINV;
    int iu = (int)floorf(fu);
    iu = iu < 0 ? 0 : (iu > 62 ? 62 : iu);
    fu -= (float)iu;
    const float* p0 = &tab[iv*64 + iu];
    const float* p1 = p0 + 64;
    float a = fmaf(fu, p0[1] - p0[0], p0[0]);
    float b = fmaf(fu, p1[1] - p1[0], p1[0]);
    res[c] = fmaf(fv, b - a, a);
  }
  *(f32x4*)&biasOut[(size_t)bg*65536 + (size_t)jj*1024 + i0] = res;
}

// ------------- MFMA attention: O = softmax(Q·K^T + bias) V -------------
__global__ __launch_bounds__(256) void attn_kernel(
    const u16* __restrict__ qTb, const u16* __restrict__ kTb, const float* __restrict__ vb,
    const float* __restrict__ biasb, u16* __restrict__ obT){
  __shared__ __align__(16) u16 qS[64*64], kS[64*64];   // swizzled (gemm pattern)
  __shared__ __align__(16) u16 vS[64*72], pS[64*72];   // pad-72 rows
  int t = threadIdx.x;
  int w = t>>6, lane = t&63, l15 = lane&15, quad = lane>>4;
  int bg = blockIdx.x>>4, itile = blockIdx.x&15;
  int i0 = itile*64;
  #pragma unroll
  for(int p=0;p<2;p++){
    int idx = p*256 + t;
    int row = idx>>3, kb = t&7;
    int sw = ((kb ^ (row&7)))*8;
    *(us8*)&qS[row*64 + sw] = *(const us8*)&qTb[(size_t)bg*65536 + (size_t)(i0+row)*64 + kb*8];
    *(us8*)&kS[row*64 + sw] = *(const us8*)&kTb[(size_t)bg*4096  + (size_t)row*64      + kb*8];
  }
  for(int e=t;e<4096;e+=256){
    int d = e>>6, j = e&63;
    vS[d*72 + j] = f2bf(vb[(size_t)bg*4096 + e]);
  }
  __syncthreads();
  f32x4 sAcc[4];
  #pragma unroll
  for(int jt=0;jt<4;jt++){
    int jg = jt*16 + l15;
    sAcc[jt] = *(const f32x4*)&biasb[(size_t)bg*65536 + (size_t)jg*1024 + i0 + w*16 + quad*4];
  }
  int ra = w*16 + l15;
  #pragma unroll
  for(int ks=0;ks<2;ks++){
    bh8 aF = *(const bh8*)&qS[ra*64 + ((ks*4+quad) ^ (ra&7))*8];
    #pragma unroll
    for(int jt=0;jt<4;jt++){
      int rb = jt*16 + l15;
      bh8 bF = *(const bh8*)&kS[rb*64 + ((ks*4+quad) ^ (rb&7))*8];
      sAcc[jt] = __builtin_amdgcn_mfma_f32_16x16x32_bf16(aF, bF, sAcc[jt], 0,0,0);
    }
  }
  #pragma unroll
  for(int reg=0;reg<4;reg++){
    float m = fmaxf(fmaxf(sAcc[0][reg], sAcc[1][reg]), fmaxf(sAcc[2][reg], sAcc[3][reg]));
    m = fmaxf(m, __shfl_xor(m, 1));
    m = fmaxf(m, __shfl_xor(m, 2));
    m = fmaxf(m, __shfl_xor(m, 4));
    m = fmaxf(m, __shfl_xor(m, 8));
    float li = 0.f;
    #pragma unroll
    for(int jt=0;jt<4;jt++){
      float e = __expf(sAcc[jt][reg] - m);
      sAcc[jt][reg] = e;
      li += e;
    }
    li += __shfl_xor(li, 1);
    li += __shfl_xor(li, 2);
    li += __shfl_xor(li, 4);
    li += __shfl_xor(li, 8);
    float inv = 1.0f / li;
    #pragma unroll
    for(int jt=0;jt<4;jt++) sAcc[jt][reg] *= inv;
  }
  #pragma unroll
  for(int jt=0;jt<4;jt++)
    #pragma unroll
    for(int reg=0;reg<4;reg++)
      pS[(w*16 + quad*4 + reg)*72 + jt*16 + l15] = f2bf(sAcc[jt][reg]);
  __syncthreads();
  f32x4 oAcc[4];
  #pragma unroll
  for(int dt=0;dt<4;dt++) oAcc[dt] = (f32x4){0.f,0.f,0.f,0.f};
  int rp = w*16 + l15;
  #pragma unroll
  for(int ks=0;ks<2;ks++){
    bh8 aP = *(const bh8*)&pS[rp*72 + ks*32 + quad*8];
    #pragma unroll
    for(int dt=0;dt<4;dt++){
      bh8 bV = *(const bh8*)&vS[(dt*16 + l15)*72 + ks*32 + quad*8];
      oAcc[dt] = __builtin_amdgcn_mfma_f32_16x16x32_bf16(aP, bV, oAcc[dt], 0,0,0);
    }
  }
  int b = bg>>3, g = bg&7;
  #pragma unroll
  for(int dt=0;dt<4;dt++)
    #pragma unroll
    for(int reg=0;reg<4;reg++){
      int i = i0 + w*16 + quad*4 + reg;
      obT[(size_t)b*524288 + (size_t)i*512 + g*64 + dt*16 + l15] = f2bf(oAcc[dt][reg]);
    }
}

extern "C" void kernel_launch(void* const* d_in, const int* in_sizes, int n_in,
                              void* d_out, int out_size, void* d_ws, size_t ws_size,
                              hipStream_t stream){
  const float* x    = (const float*)d_in[0];
  const float* n1g  = (const float*)d_in[1];
  const float* n1b  = (const float*)d_in[2];
  const float* n2g  = (const float*)d_in[3];
  const float* n2b  = (const float*)d_in[4];
  const float* qw   = (const float*)d_in[5];
  const float* kw   = (const float*)d_in[6];
  const float* vw   = (const float*)d_in[7];
  const float* dww  = (const float*)d_in[8];
  const float* dwb  = (const float*)d_in[9];
  const float* pww  = (const float*)d_in[10];
  const float* cw0  = (const float*)d_in[11];
  const float* cb0  = (const float*)d_in[12];
  const float* cw1  = (const float*)d_in[13];
  const float* cb1  = (const float*)d_in[14];
  const float* cw2  = (const float*)d_in[15];
  const float* cb2  = (const float*)d_in[16];
  const float* ow   = (const float*)d_in[17];
  const float* obb  = (const float*)d_in[18];
  const float* m1w  = (const float*)d_in[19];
  const float* m1bi = (const float*)d_in[20];
  const float* m2w  = (const float*)d_in[21];
  const float* m2bi = (const float*)d_in[22];
  float* out = (float*)d_out;          // reference output dtype is float32
  float* ws = (float*)d_ws;

  float* xn     = ws;                       // 1M f32: bn1 normalized (c-major, for sample)
  float* x2     = ws + 1048576;             // 1M f32: outproj out (res for mlp2, src for bn2)
  float* q      = ws + 2097152;             // 1M f32 [bg][c][p], dead after dwconv
  float* biasb  = ws + 3145728;             // 1M f32, dead after attn
  u16*   hT     = (u16*)(ws + 2097152);     // 4M u16 over dead {q,biasb}: mlp1 out [b][p][c2048]
  u16*   attnT  = (u16*)(ws + 4194304);     // 1M u16: attn out [b][p][c512]
  u16*   xnT    = (u16*)(ws + 4718592);     // 1M u16: bn1 T [bg][p][c64]; reused as bn2 T [b][p][c512]
  float* tab    = ws + 5242880;             // 4096 f32 CPB table
  u16*   kTb    = (u16*)(ws + 5275648);     // 64K u16: k bf16 [bg][j][d]
  float* vbuf   = ws + 5341184;             // 64K f32 [bg][d][j]
  float* offg   = ws + 5406720;             // 64K f32 (aliased as bn stats when offg dead)
  float* bnAB   = offg;                     // 1024 f32 alias (disjoint lifetime)
  float* vgrid  = ws + 5472256;             // 2K f32
  u16*   wbf    = (u16*)(ws + 5474304);     // 2457600 u16 bf16 weights
  u16*   qTb    = (u16*)(ws + 6703104);     // 1M u16: q bf16 [bg][p][d], pre-scaled by 0.125
  u16 *qwb = wbf, *kwb = wbf+32768, *vwb = wbf+65536, *owb = wbf+98304;
  u16 *m1wb = wbf+360448, *m2wb = wbf+1409024;

  // prep: cvtw (2400) + bnstat1 (512) + tabbuild v2 (256) in one dispatch
  prep_kernel<<<3168,256,0,stream>>>(qw,kw,vw,ow,m1w,m2w,wbf,
                                     x,n1g,n1b,bnAB,
                                     cw0,cb0,cw1,cb1,cw2,cb2,tab);
  bntrans_kernel<<<dim3(16,8,2),256,0,stream>>>(x, bnAB, xn, xnT, 0);
  // q: dual output — f32 [bg][c][p] for dwconv + bf16 [bg][p][d] (x0.125) for MFMA attn
  gemm_lds<1,2><<<dim3(16,1,16),256,0,stream>>>(qwb, xnT, q, qTb, nullptr, nullptr,
                                                64,64,1024, 7, 4096, 0);
  dwconv_kernel<<<256,256,0,stream>>>(q, dww, dwb, offg);
  // fused pwgrid + sample + k-gemm + v-gemm (per-bg blocks; kv tile lives in LDS)
  samplekv_kernel<<<16,256,0,stream>>>(xn, offg, pww, kwb, vwb, vgrid, kTb, vbuf);
  biaseval_kernel<<<1024,256,0,stream>>>(vgrid, tab, biasb);
  attn_kernel<<<256,256,0,stream>>>(qTb, kTb, vbuf, biasb, attnT);
  gemm_lds<1,0><<<dim3(16,8,2),256,0,stream>>>(owb, attnT, x2, nullptr, obb, x,
                                               512,512,1024, 0,0,0);
  bnstat_kernel<<<512,256,0,stream>>>(x2, n2g, n2b, bnAB);
  bntrans_kernel<<<dim3(16,8,2),256,0,stream>>>(x2, bnAB, nullptr, xnT, 1);
  // mlp1: NT=2 (64m x 128n tile), grid 512 blocks
  gemm_lds<2,1><<<dim3(8,32,2),256,0,stream>>>(m1wb, xnT, nullptr, hT, m1bi, nullptr,
                                               2048,512,1024, 0,0,1);
  gemm_lds<1,0><<<dim3(16,8,2),256,0,stream>>>(m2wb, hT, out, nullptr, m2bi, x2,
                                               512,2048,1024, 0,0,0);
}